// Round 5
// baseline (146.806 us; speedup 1.0000x reference)
//
#include <hip/hip_runtime.h>

// ---------------------------------------------------------------------------
// DeltaThetaGammaCLEVRN — f32 I/O. Oscillator phases are dead code (amplitude
// ODE is phase-independent, ad0=at0=1 is a fixed point). Per sample:
//   sf[16] = mean_n scene;  g = sigmoid(sf@Ws+bs);  20x: g += .01*(g-g^3)
//   h = relu(beff + [query|g] @ W12);  logits = h@W2+b2; log_softmax.
// Stage 2 via 16x16x32 bf16 MFMA, split-bf16 compensation (Xh*Wh+Xh*Wl+Xl*Wh).
// Round-12 (this round): prep path collapsed to ONE kernel (17 blocks):
//   each fragment block (0..15) recomputes ONLY its own 16-col x 32-row slice
//   of Wq_fold = qw @ w1[88:152] (2 64-FMA chains/thread at 256 thr — fully
//   parallel, unlike R8's 4-block serial dot) and packs with prep2's original
//   fully-coalesced 16B/lane stores (unlike R10's 2B scatter). Block 16 =
//   b_eff. Deletes one launch + one graph gap + the WS_WQ global round-trip.
//   dtg_main unchanged from R11 (single-wave 64-thr blocks, 16 samples,
//   4096 blocks, barrier-free; measured 145.1 total).
// Counters context: top dispatches are the harness's 256 MiB ws-poison fills
// (~40.5 us each) — untouchable; we optimize the remaining ~24 us.
// ---------------------------------------------------------------------------

typedef __attribute__((ext_vector_type(8))) short short8;   // 8 bf16 = 4 VGPR
typedef __attribute__((ext_vector_type(4))) float f32x4;
typedef __attribute__((ext_vector_type(2))) float f32x2;    // -> v_pk_*_f32

__device__ __forceinline__ unsigned short f2bf(float f) {
  unsigned u = __float_as_uint(f);
  return (unsigned short)((u + 0x7FFFu + ((u >> 16) & 1u)) >> 16);   // RNE
}
__device__ __forceinline__ float bf2f(unsigned short s) {
  return __uint_as_float(((unsigned)s) << 16);
}

// d_ws layout (f32 word offsets)
#define WS_BEFF  3840   // [64] b_eff
#define WS_WHF   3904   // 16 frags x 64 lanes x 8 bf16 (hi)  = 4096 words
#define WS_WLF   8000   // 16 frags x 64 lanes x 8 bf16 (lo)  = 4096 words

// 17 blocks x 256 threads.
//   blocks 0..15 (frag = blk; nt=blk>>2, kk=blk&3):
//     kk<2: recompute Wq_fold slice rows kk*32..+31 (cap 60) x cols nt*16..+15
//           into LDS (2 indep 64-FMA dots/thread, coalesced float2 w1 loads),
//     then lanes 0..63 pack frag (nt,kk) in MFMA B order with bf16 hi+lo,
//     16B/lane coalesced stores: elem j = W[kk*32+(l>>4)*8+j][nt*16+(l&15)],
//     W rows 0..59 = Wq_fold, 60..123 = ro_w1 rows 24..87, 124..127 = 0.
//   block 16: b_eff[64] = b1 + sum_{r<24} w1[r] + qb @ w1[88:152].
__global__ __launch_bounds__(256) void dtg_prep(
    const float* __restrict__ qw, const float* __restrict__ qb,
    const float* __restrict__ w1, const float* __restrict__ b1,
    float* __restrict__ ws)
{
  __shared__ float sm[512];        // frag blocks: wq tile [32][16]; beff: [256]
  const int blk = blockIdx.x, tid = threadIdx.x;
  if (blk < 16) {
    const int nt = blk >> 2, kk = blk & 3;
    if (kk < 2) {                  // rows kk*32..+31 hold Wq_fold (k<60)
      const int rl = tid >> 3;                 // 0..31
      const int r  = kk * 32 + rl;
      const int cp = (tid & 7) * 2;            // col pair in 0..15
      if (r < 60) {
        const float* w1c = w1 + 88 * 64 + nt * 16 + cp;
        float d0 = 0.f, d1 = 0.f;
#pragma unroll 8
        for (int j2 = 0; j2 < 64; ++j2) {
          const float  qv = qw[r * 64 + j2];
          const float2 wv = *(const float2*)(w1c + j2 * 64);
          d0 = fmaf(qv, wv.x, d0);
          d1 = fmaf(qv, wv.y, d1);
        }
        sm[rl * 16 + cp]     = d0;
        sm[rl * 16 + cp + 1] = d1;
      }
    }
    __syncthreads();
    if (tid < 64) {
      const int lane = tid;
      const int idx  = blk * 64 + lane;
      const int nl   = lane & 15, q = lane >> 4;
      const int n    = nt * 16 + nl;
      unsigned short* dh = (unsigned short*)(ws + WS_WHF);
      unsigned short* dl = (unsigned short*)(ws + WS_WLF);
      unsigned short hh[8], ll[8];
#pragma unroll
      for (int j = 0; j < 8; ++j) {
        const int k = kk * 32 + q * 8 + j;
        float w;
        if      (k < 60)  w = sm[(k - kk * 32) * 16 + nl];
        else if (k < 124) w = w1[(k - 36) * 64 + n];     // ro_w1 row 24+k-60
        else              w = 0.f;
        hh[j] = f2bf(w);
        ll[j] = f2bf(w - bf2f(hh[j]));
      }
#pragma unroll
      for (int j = 0; j < 8; ++j) { dh[idx * 8 + j] = hh[j]; dl[idx * 8 + j] = ll[j]; }
    }
  } else {   // blk == 16: b_eff
    const int c = tid & 63, p = tid >> 6;
    float acc = 0.f;
    if (p == 0) {
      acc = b1[c];
      for (int r = 0; r < 24; ++r) acc += w1[r * 64 + c];
    }
    for (int j = p * 16; j < p * 16 + 16; ++j)
      acc = fmaf(qb[j], w1[(88 + j) * 64 + c], acc);
    sm[tid] = acc;
    __syncthreads();
    if (tid < 64)
      ws[WS_BEFF + tid] = sm[tid] + sm[64 + tid] + sm[128 + tid] + sm[192 + tid];
  }
}

// LDS layout (bytes) — 16 samples per single-wave block
#define XH_OFF 0                   // Xh [16 rows][128 k] bf16, row stride 272 B
#define XL_OFF 4352                // Xl [16 rows][ 64 k] bf16, row stride 144 B
#define SF_OFF 6656                // sf [16][20] f32 (scene means, transposed)
#define L_BYTES (6656 + 16*20*4)   // 7,936 B -> 16 blocks/CU (VGPR-limited)

__global__ __launch_bounds__(64, 4) void dtg_main(
    const float* __restrict__ scene,
    const float* __restrict__ query,
    const float* __restrict__ sw,    // scene_w [16][64]
    const float* __restrict__ sb,    // scene_b [64]
    const float* __restrict__ w2,    // ro_w2 [64][2]
    const float* __restrict__ b2,    // ro_b2 [2]
    const float* __restrict__ ws,
    float* __restrict__ outf)
{
  __shared__ __align__(16) char smem[L_BYTES];
  const int tid = threadIdx.x;     // == lane, single wave
  const int blk = blockIdx.x;
  float* sf = (float*)(smem + SF_OFF);

  // ---- phase A: scene mean -> sf_t; query -> Xh/Xl rows (A-layout)
  {
    const int s = tid >> 2, q = tid & 3;             // sample 0..15, quad
    const float4* sp = (const float4*)scene + (size_t)blk * 512;  // 16*32 f4
    float4 a = make_float4(0.f, 0.f, 0.f, 0.f);
#pragma unroll
    for (int n = 0; n < 8; ++n) {
      float4 v = sp[s * 32 + n * 4 + q];
      a.x += v.x; a.y += v.y; a.z += v.z; a.w += v.w;
    }
    sf[(4 * q + 0) * 20 + s] = a.x * 0.125f;
    sf[(4 * q + 1) * 20 + s] = a.y * 0.125f;
    sf[(4 * q + 2) * 20 + s] = a.z * 0.125f;
    sf[(4 * q + 3) * 20 + s] = a.w * 0.125f;

    const float4* qp = (const float4*)query + (size_t)blk * 240;  // 16*15 f4
#pragma unroll
    for (int m = 0; m < 4; ++m) {
      const int f4i = q + 4 * m;
      if (f4i < 15) {
        float4 v = qp[s * 15 + f4i];
        const float xs[4] = {v.x, v.y, v.z, v.w};
        unsigned short h[4], l[4];
#pragma unroll
        for (int j = 0; j < 4; ++j) {
          h[j] = f2bf(xs[j]);
          l[j] = f2bf(xs[j] - bf2f(h[j]));
        }
        uint2 ph, pl;
        ph.x = (unsigned)h[0] | ((unsigned)h[1] << 16);
        ph.y = (unsigned)h[2] | ((unsigned)h[3] << 16);
        pl.x = (unsigned)l[0] | ((unsigned)l[1] << 16);
        pl.y = (unsigned)l[2] | ((unsigned)l[3] << 16);
        *(uint2*)(smem + XH_OFF + s * 272 + f4i * 8) = ph;
        *(uint2*)(smem + XL_OFF + s * 144 + f4i * 8) = pl;
      }
    }
    if (tid < 16) {   // zero pads: Xh k 124..127, Xl k 60..63
      *(uint2*)(smem + XH_OFF + tid * 272 + 248) = make_uint2(0u, 0u);
      *(uint2*)(smem + XL_OFF + tid * 144 + 120) = make_uint2(0u, 0u);
    }
  }
  __syncthreads();   // single-wave wg: compiler elides s_barrier, keeps waits

  // ---- phase B: stage-1 (4x4 tile, packed f32) + sigmoid + Euler,
  //      g -> Xh rows 60..123. float2 lanes -> v_pk_fma_f32 (2x VALU rate).
  const int sgrp = tid >> 4, cgrp = tid & 15;        // sgrp 0..3
  {
    f32x2 ga[4][2];                                  // [si][col pair]
    float4 bsv = ((const float4*)sb)[cgrp];
    const f32x2 b01 = {bsv.x, bsv.y};
    const f32x2 b23 = {bsv.z, bsv.w};
#pragma unroll
    for (int si = 0; si < 4; ++si) { ga[si][0] = b01; ga[si][1] = b23; }
    const float4* swp = (const float4*)sw;
#pragma unroll 4
    for (int k = 0; k < 16; ++k) {
      float4 xv = *(const float4*)(sf + k * 20 + 4 * sgrp);
      float4 wv = swp[k * 16 + cgrp];
      const f32x2 w01 = {wv.x, wv.y};
      const f32x2 w23 = {wv.z, wv.w};
      const float xs[4] = {xv.x, xv.y, xv.z, xv.w};
#pragma unroll
      for (int si = 0; si < 4; ++si) {
        const f32x2 xb = {xs[si], xs[si]};
        ga[si][0] += xb * w01;        // contracts to v_pk_fma_f32
        ga[si][1] += xb * w23;
      }
    }
#pragma unroll
    for (int si = 0; si < 4; ++si)
#pragma unroll
      for (int cp = 0; cp < 2; ++cp) {
        ga[si][cp].x = __builtin_amdgcn_rcpf(1.f + __expf(-ga[si][cp].x));
        ga[si][cp].y = __builtin_amdgcn_rcpf(1.f + __expf(-ga[si][cp].y));
      }
    const f32x2 c01 = {0.01f, 0.01f};
    for (int st = 0; st < 20; ++st) {
#pragma unroll
      for (int si = 0; si < 4; ++si)
#pragma unroll
        for (int cp = 0; cp < 2; ++cp) {
          const f32x2 a = ga[si][cp];
          const f32x2 t = a * a;          // v_pk_mul_f32
          const f32x2 d = a - t * a;      // v_pk_fma_f32 (neg)
          ga[si][cp] = c01 * d + a;       // v_pk_fma_f32
        }
    }
#pragma unroll
    for (int si = 0; si < 4; ++si) {   // 4 bf16 (cols 4cgrp..+3), hi only
      uint2 pw;
      pw.x = (unsigned)f2bf(ga[si][0].x) | ((unsigned)f2bf(ga[si][0].y) << 16);
      pw.y = (unsigned)f2bf(ga[si][1].x) | ((unsigned)f2bf(ga[si][1].y) << 16);
      *(uint2*)(smem + XH_OFF + (4 * sgrp + si) * 272 + 120 + 8 * cgrp) = pw;
    }
  }
  __syncthreads();   // single-wave wg: elided barrier, lgkmcnt wait only

  // ---- phase C: MFMA. the wave -> 16 samples x all 64 cols, K=128.
  const int lane = tid;
  const int quad = lane >> 4;
  const int mrow = lane & 15;
  const char* arow = smem + XH_OFF + mrow * 272 + quad * 16;
  short8 Ah0 = *(const short8*)(arow + 0);
  short8 Ah1 = *(const short8*)(arow + 64);
  short8 Ah2 = *(const short8*)(arow + 128);
  short8 Ah3 = *(const short8*)(arow + 192);
  const char* lrow = smem + XL_OFF + mrow * 144 + quad * 16;
  short8 Al0 = *(const short8*)(lrow + 0);
  short8 Al1 = *(const short8*)(lrow + 64);

  // per-col constants preloaded (8 L2-hot loads, issued together)
  float  be[4];
  float2 w2v4[4];
#pragma unroll
  for (int nt = 0; nt < 4; ++nt) {
    const int col = nt * 16 + (lane & 15);
    be[nt]   = ws[WS_BEFF + col];
    w2v4[nt] = ((const float2*)w2)[col];
  }

  const short8* bhp = (const short8*)(ws + WS_WHF) + lane;
  const short8* blp = (const short8*)(ws + WS_WLF) + lane;
  // prefetch nt=0 fragments
  short8 c0 = bhp[0], c1 = bhp[64], c2 = bhp[128], c3 = bhp[192];
  short8 c4 = blp[0], c5 = blp[64];

  float l0[4] = {0.f, 0.f, 0.f, 0.f}, l1[4] = {0.f, 0.f, 0.f, 0.f};
#pragma unroll
  for (int nt = 0; nt < 4; ++nt) {
    short8 n0 = c0, n1 = c1, n2 = c2, n3 = c3, n4 = c4, n5 = c5;
    if (nt < 3) {                       // prefetch nt+1 during this nt's MFMAs
      const short8* nh = bhp + 256;
      const short8* nl = blp + 256;
      n0 = nh[0]; n1 = nh[64]; n2 = nh[128]; n3 = nh[192];
      n4 = nl[0]; n5 = nl[64];
    }
    // remaining hi*lo operands issued before the MFMA chain so their ~200 cyc
    // L2 latency overlaps the first 8 MFMAs
    short8 x4 = blp[128], x5 = blp[192];
    f32x4 acc = {0.f, 0.f, 0.f, 0.f};
    acc = __builtin_amdgcn_mfma_f32_16x16x32_bf16(Ah0, c0, acc, 0, 0, 0);
    acc = __builtin_amdgcn_mfma_f32_16x16x32_bf16(Ah1, c1, acc, 0, 0, 0);
    acc = __builtin_amdgcn_mfma_f32_16x16x32_bf16(Ah2, c2, acc, 0, 0, 0);
    acc = __builtin_amdgcn_mfma_f32_16x16x32_bf16(Ah3, c3, acc, 0, 0, 0);
    acc = __builtin_amdgcn_mfma_f32_16x16x32_bf16(Ah0, c4, acc, 0, 0, 0);
    acc = __builtin_amdgcn_mfma_f32_16x16x32_bf16(Ah1, c5, acc, 0, 0, 0);
    acc = __builtin_amdgcn_mfma_f32_16x16x32_bf16(Al0, c0, acc, 0, 0, 0);
    acc = __builtin_amdgcn_mfma_f32_16x16x32_bf16(Al1, c1, acc, 0, 0, 0);
    acc = __builtin_amdgcn_mfma_f32_16x16x32_bf16(Ah2, x4, acc, 0, 0, 0);
    acc = __builtin_amdgcn_mfma_f32_16x16x32_bf16(Ah3, x5, acc, 0, 0, 0);
#pragma unroll
    for (int r = 0; r < 4; ++r) {
      float h = fmaxf(acc[r] + be[nt], 0.f);
      l0[r] = fmaf(h, w2v4[nt].x, l0[r]);
      l1[r] = fmaf(h, w2v4[nt].y, l1[r]);
    }
    bhp += 256; blp += 256;
    c0 = n0; c1 = n1; c2 = n2; c3 = n3; c4 = n4; c5 = n5;
  }
  // reduce over the 16 column-lanes (lane bits 0..3)
#pragma unroll
  for (int m = 1; m < 16; m <<= 1) {
#pragma unroll
    for (int r = 0; r < 4; ++r) {
      l0[r] += __shfl_xor(l0[r], m);
      l1[r] += __shfl_xor(l1[r], m);
    }
  }
  if ((lane & 15) == 0) {
    const float bb0 = b2[0], bb1 = b2[1];
    float rr[8];
#pragma unroll
    for (int r = 0; r < 4; ++r) {
      float a0 = l0[r] + bb0, a1 = l1[r] + bb1;
      float mx  = fmaxf(a0, a1);
      float e0  = __expf(a0 - mx), e1 = __expf(a1 - mx);
      float lse = mx + __logf(e0 + e1);
      rr[2 * r] = a0 - lse; rr[2 * r + 1] = a1 - lse;
    }
    const int base = blk * 16 + quad * 4;              // 4 consecutive samples
    float4* op = (float4*)(outf + base * 2);
    op[0] = make_float4(rr[0], rr[1], rr[2], rr[3]);
    op[1] = make_float4(rr[4], rr[5], rr[6], rr[7]);
  }
}

extern "C" void kernel_launch(void* const* d_in, const int* in_sizes, int n_in,
                              void* d_out, int out_size, void* d_ws, size_t ws_size,
                              hipStream_t stream)
{
  const float* scene = (const float*)d_in[0];
  const float* query = (const float*)d_in[1];
  // d_in[2..7] = phases/freqs: dead code w.r.t. the output, never read
  const float* sw = (const float*)d_in[8];
  const float* sb = (const float*)d_in[9];
  const float* qw = (const float*)d_in[10];
  const float* qb = (const float*)d_in[11];
  const float* w1 = (const float*)d_in[12];
  const float* b1 = (const float*)d_in[13];
  const float* w2 = (const float*)d_in[14];
  const float* b2 = (const float*)d_in[15];
  float* ws = (float*)d_ws;
  const int B = in_sizes[0] / 128;   // 65536

  hipLaunchKernelGGL(dtg_prep, dim3(17), dim3(256), 0, stream, qw, qb, w1, b1, ws);
  hipLaunchKernelGGL(dtg_main, dim3(B / 16), dim3(64), 0, stream,
                     scene, query, sw, sb, w2, b2, ws, (float*)d_out);
}

// Round 6
// 143.952 us; speedup vs baseline: 1.0198x; 1.0198x over previous
//
#include <hip/hip_runtime.h>

// ---------------------------------------------------------------------------
// DeltaThetaGammaCLEVRN — f32 I/O. Oscillator phases are dead code (amplitude
// ODE is phase-independent, ad0=at0=1 is a fixed point). Per sample:
//   sf[16] = mean_n scene;  g = sigmoid(sf@Ws+bs);  20x: g += .01*(g-g^3)
//   h = relu(beff + [query|g] @ W12);  logits = h@W2+b2; log_softmax.
// Stage 2 via 16x16x32 bf16 MFMA, split-bf16 compensation (Xh*Wh+Xh*Wl+Xl*Wh).
// Round-13 (FINAL): exact revert to the R11 configuration — the best measured
//   (145.1 us). R12's slice-recompute prep merge regressed (serial 64-FMA
//   chain on 16 blocks ≈ the launch it saved). Six structural variants over
//   the session land in a 145.1-146.8 band while the harness's three 256 MiB
//   ws-poison fills (~121 us, 83% of measured time) vary ±2 us run-to-run:
//   remaining deltas are below measurement noise.
//   Structure: two-kernel prep (61-block parallel Wq_fold + 16-block coalesced
//   fragment packer) + single-wave barrier-free dtg_main (64 thr, 16 samples,
//   4096 blocks; ~8.5 us HBM floor for scene 33.5 MB + query 15.7 MB).
// ---------------------------------------------------------------------------

typedef __attribute__((ext_vector_type(8))) short short8;   // 8 bf16 = 4 VGPR
typedef __attribute__((ext_vector_type(4))) float f32x4;
typedef __attribute__((ext_vector_type(2))) float f32x2;    // -> v_pk_*_f32

__device__ __forceinline__ unsigned short f2bf(float f) {
  unsigned u = __float_as_uint(f);
  return (unsigned short)((u + 0x7FFFu + ((u >> 16) & 1u)) >> 16);   // RNE
}
__device__ __forceinline__ float bf2f(unsigned short s) {
  return __uint_as_float(((unsigned)s) << 16);
}

// d_ws layout (f32 word offsets)
#define WS_WQ    0      // [60][64] Wq_fold = query_w @ ro_w1[88:152]
#define WS_BEFF  3840   // [64] b_eff
#define WS_WHF   3904   // 16 frags x 64 lanes x 8 bf16 (hi)  = 4096 words
#define WS_WLF   8000   // 16 frags x 64 lanes x 8 bf16 (lo)  = 4096 words

__global__ __launch_bounds__(256) void dtg_prep(
    const float* __restrict__ qw, const float* __restrict__ qb,
    const float* __restrict__ w1, const float* __restrict__ b1,
    float* __restrict__ ws)
{
  __shared__ float sm[256];
  const int blk = blockIdx.x, tid = threadIdx.x;
  const int c = tid & 63, p = tid >> 6;
  if (blk < 60) {
    float acc = 0.f;
    for (int j = p * 16; j < p * 16 + 16; ++j)
      acc = fmaf(qw[blk * 64 + j], w1[(88 + j) * 64 + c], acc);
    sm[tid] = acc;
    __syncthreads();
    if (tid < 64)
      ws[WS_WQ + blk * 64 + tid] = sm[tid] + sm[64 + tid] + sm[128 + tid] + sm[192 + tid];
  } else {
    float acc = 0.f;
    if (p == 0) {
      acc = b1[c];
      for (int r = 0; r < 24; ++r) acc += w1[r * 64 + c];
    }
    for (int j = p * 16; j < p * 16 + 16; ++j)
      acc = fmaf(qb[j], w1[(88 + j) * 64 + c], acc);
    sm[tid] = acc;
    __syncthreads();
    if (tid < 64)
      ws[WS_BEFF + tid] = sm[tid] + sm[64 + tid] + sm[128 + tid] + sm[192 + tid];
  }
}

// Pack W12 (k 0..59 = Wq_fold, 60..123 = ro_w1 rows 24..87, 124..127 = 0)
// into MFMA B-fragment lane order: frag (nt,kk), lane l, element j =
// W[kk*32 + (l>>4)*8 + j][nt*16 + (l&15)], bf16 hi + lo.
__global__ __launch_bounds__(64) void dtg_prep2(
    const float* __restrict__ w1, float* __restrict__ ws)
{
  const int frag = blockIdx.x;            // 0..15
  const int lane = threadIdx.x;           // 0..63
  const int idx  = frag * 64 + lane;
  const int nt = frag >> 2, kk = frag & 3;
  const int n = nt * 16 + (lane & 15), q = lane >> 4;
  unsigned short* dh = (unsigned short*)(ws + WS_WHF);
  unsigned short* dl = (unsigned short*)(ws + WS_WLF);
  unsigned short hh[8], ll[8];
#pragma unroll
  for (int j = 0; j < 8; ++j) {
    const int k = kk * 32 + q * 8 + j;
    float w;
    if      (k < 60)  w = ws[WS_WQ + k * 64 + n];
    else if (k < 124) w = w1[(24 + k - 60) * 64 + n];
    else              w = 0.f;
    hh[j] = f2bf(w);
    ll[j] = f2bf(w - bf2f(hh[j]));
  }
#pragma unroll
  for (int j = 0; j < 8; ++j) { dh[idx * 8 + j] = hh[j]; dl[idx * 8 + j] = ll[j]; }
}

// LDS layout (bytes) — 16 samples per single-wave block
#define XH_OFF 0                   // Xh [16 rows][128 k] bf16, row stride 272 B
#define XL_OFF 4352                // Xl [16 rows][ 64 k] bf16, row stride 144 B
#define SF_OFF 6656                // sf [16][20] f32 (scene means, transposed)
#define L_BYTES (6656 + 16*20*4)   // 7,936 B -> 16 blocks/CU (VGPR-limited)

__global__ __launch_bounds__(64, 4) void dtg_main(
    const float* __restrict__ scene,
    const float* __restrict__ query,
    const float* __restrict__ sw,    // scene_w [16][64]
    const float* __restrict__ sb,    // scene_b [64]
    const float* __restrict__ w2,    // ro_w2 [64][2]
    const float* __restrict__ b2,    // ro_b2 [2]
    const float* __restrict__ ws,
    float* __restrict__ outf)
{
  __shared__ __align__(16) char smem[L_BYTES];
  const int tid = threadIdx.x;     // == lane, single wave
  const int blk = blockIdx.x;
  float* sf = (float*)(smem + SF_OFF);

  // ---- phase A: scene mean -> sf_t; query -> Xh/Xl rows (A-layout)
  {
    const int s = tid >> 2, q = tid & 3;             // sample 0..15, quad
    const float4* sp = (const float4*)scene + (size_t)blk * 512;  // 16*32 f4
    float4 a = make_float4(0.f, 0.f, 0.f, 0.f);
#pragma unroll
    for (int n = 0; n < 8; ++n) {
      float4 v = sp[s * 32 + n * 4 + q];
      a.x += v.x; a.y += v.y; a.z += v.z; a.w += v.w;
    }
    sf[(4 * q + 0) * 20 + s] = a.x * 0.125f;
    sf[(4 * q + 1) * 20 + s] = a.y * 0.125f;
    sf[(4 * q + 2) * 20 + s] = a.z * 0.125f;
    sf[(4 * q + 3) * 20 + s] = a.w * 0.125f;

    const float4* qp = (const float4*)query + (size_t)blk * 240;  // 16*15 f4
#pragma unroll
    for (int m = 0; m < 4; ++m) {
      const int f4i = q + 4 * m;
      if (f4i < 15) {
        float4 v = qp[s * 15 + f4i];
        const float xs[4] = {v.x, v.y, v.z, v.w};
        unsigned short h[4], l[4];
#pragma unroll
        for (int j = 0; j < 4; ++j) {
          h[j] = f2bf(xs[j]);
          l[j] = f2bf(xs[j] - bf2f(h[j]));
        }
        uint2 ph, pl;
        ph.x = (unsigned)h[0] | ((unsigned)h[1] << 16);
        ph.y = (unsigned)h[2] | ((unsigned)h[3] << 16);
        pl.x = (unsigned)l[0] | ((unsigned)l[1] << 16);
        pl.y = (unsigned)l[2] | ((unsigned)l[3] << 16);
        *(uint2*)(smem + XH_OFF + s * 272 + f4i * 8) = ph;
        *(uint2*)(smem + XL_OFF + s * 144 + f4i * 8) = pl;
      }
    }
    if (tid < 16) {   // zero pads: Xh k 124..127, Xl k 60..63
      *(uint2*)(smem + XH_OFF + tid * 272 + 248) = make_uint2(0u, 0u);
      *(uint2*)(smem + XL_OFF + tid * 144 + 120) = make_uint2(0u, 0u);
    }
  }
  __syncthreads();   // single-wave wg: compiler elides s_barrier, keeps waits

  // ---- phase B: stage-1 (4x4 tile, packed f32) + sigmoid + Euler,
  //      g -> Xh rows 60..123. float2 lanes -> v_pk_fma_f32 (2x VALU rate).
  const int sgrp = tid >> 4, cgrp = tid & 15;        // sgrp 0..3
  {
    f32x2 ga[4][2];                                  // [si][col pair]
    float4 bsv = ((const float4*)sb)[cgrp];
    const f32x2 b01 = {bsv.x, bsv.y};
    const f32x2 b23 = {bsv.z, bsv.w};
#pragma unroll
    for (int si = 0; si < 4; ++si) { ga[si][0] = b01; ga[si][1] = b23; }
    const float4* swp = (const float4*)sw;
#pragma unroll 4
    for (int k = 0; k < 16; ++k) {
      float4 xv = *(const float4*)(sf + k * 20 + 4 * sgrp);
      float4 wv = swp[k * 16 + cgrp];
      const f32x2 w01 = {wv.x, wv.y};
      const f32x2 w23 = {wv.z, wv.w};
      const float xs[4] = {xv.x, xv.y, xv.z, xv.w};
#pragma unroll
      for (int si = 0; si < 4; ++si) {
        const f32x2 xb = {xs[si], xs[si]};
        ga[si][0] += xb * w01;        // contracts to v_pk_fma_f32
        ga[si][1] += xb * w23;
      }
    }
#pragma unroll
    for (int si = 0; si < 4; ++si)
#pragma unroll
      for (int cp = 0; cp < 2; ++cp) {
        ga[si][cp].x = __builtin_amdgcn_rcpf(1.f + __expf(-ga[si][cp].x));
        ga[si][cp].y = __builtin_amdgcn_rcpf(1.f + __expf(-ga[si][cp].y));
      }
    const f32x2 c01 = {0.01f, 0.01f};
    for (int st = 0; st < 20; ++st) {
#pragma unroll
      for (int si = 0; si < 4; ++si)
#pragma unroll
        for (int cp = 0; cp < 2; ++cp) {
          const f32x2 a = ga[si][cp];
          const f32x2 t = a * a;          // v_pk_mul_f32
          const f32x2 d = a - t * a;      // v_pk_fma_f32 (neg)
          ga[si][cp] = c01 * d + a;       // v_pk_fma_f32
        }
    }
#pragma unroll
    for (int si = 0; si < 4; ++si) {   // 4 bf16 (cols 4cgrp..+3), hi only
      uint2 pw;
      pw.x = (unsigned)f2bf(ga[si][0].x) | ((unsigned)f2bf(ga[si][0].y) << 16);
      pw.y = (unsigned)f2bf(ga[si][1].x) | ((unsigned)f2bf(ga[si][1].y) << 16);
      *(uint2*)(smem + XH_OFF + (4 * sgrp + si) * 272 + 120 + 8 * cgrp) = pw;
    }
  }
  __syncthreads();   // single-wave wg: elided barrier, lgkmcnt wait only

  // ---- phase C: MFMA. the wave -> 16 samples x all 64 cols, K=128.
  const int lane = tid;
  const int quad = lane >> 4;
  const int mrow = lane & 15;
  const char* arow = smem + XH_OFF + mrow * 272 + quad * 16;
  short8 Ah0 = *(const short8*)(arow + 0);
  short8 Ah1 = *(const short8*)(arow + 64);
  short8 Ah2 = *(const short8*)(arow + 128);
  short8 Ah3 = *(const short8*)(arow + 192);
  const char* lrow = smem + XL_OFF + mrow * 144 + quad * 16;
  short8 Al0 = *(const short8*)(lrow + 0);
  short8 Al1 = *(const short8*)(lrow + 64);

  // per-col constants preloaded (8 L2-hot loads, issued together)
  float  be[4];
  float2 w2v4[4];
#pragma unroll
  for (int nt = 0; nt < 4; ++nt) {
    const int col = nt * 16 + (lane & 15);
    be[nt]   = ws[WS_BEFF + col];
    w2v4[nt] = ((const float2*)w2)[col];
  }

  const short8* bhp = (const short8*)(ws + WS_WHF) + lane;
  const short8* blp = (const short8*)(ws + WS_WLF) + lane;
  // prefetch nt=0 fragments
  short8 c0 = bhp[0], c1 = bhp[64], c2 = bhp[128], c3 = bhp[192];
  short8 c4 = blp[0], c5 = blp[64];

  float l0[4] = {0.f, 0.f, 0.f, 0.f}, l1[4] = {0.f, 0.f, 0.f, 0.f};
#pragma unroll
  for (int nt = 0; nt < 4; ++nt) {
    short8 n0 = c0, n1 = c1, n2 = c2, n3 = c3, n4 = c4, n5 = c5;
    if (nt < 3) {                       // prefetch nt+1 during this nt's MFMAs
      const short8* nh = bhp + 256;
      const short8* nl = blp + 256;
      n0 = nh[0]; n1 = nh[64]; n2 = nh[128]; n3 = nh[192];
      n4 = nl[0]; n5 = nl[64];
    }
    // remaining hi*lo operands issued before the MFMA chain so their ~200 cyc
    // L2 latency overlaps the first 8 MFMAs
    short8 x4 = blp[128], x5 = blp[192];
    f32x4 acc = {0.f, 0.f, 0.f, 0.f};
    acc = __builtin_amdgcn_mfma_f32_16x16x32_bf16(Ah0, c0, acc, 0, 0, 0);
    acc = __builtin_amdgcn_mfma_f32_16x16x32_bf16(Ah1, c1, acc, 0, 0, 0);
    acc = __builtin_amdgcn_mfma_f32_16x16x32_bf16(Ah2, c2, acc, 0, 0, 0);
    acc = __builtin_amdgcn_mfma_f32_16x16x32_bf16(Ah3, c3, acc, 0, 0, 0);
    acc = __builtin_amdgcn_mfma_f32_16x16x32_bf16(Ah0, c4, acc, 0, 0, 0);
    acc = __builtin_amdgcn_mfma_f32_16x16x32_bf16(Ah1, c5, acc, 0, 0, 0);
    acc = __builtin_amdgcn_mfma_f32_16x16x32_bf16(Al0, c0, acc, 0, 0, 0);
    acc = __builtin_amdgcn_mfma_f32_16x16x32_bf16(Al1, c1, acc, 0, 0, 0);
    acc = __builtin_amdgcn_mfma_f32_16x16x32_bf16(Ah2, x4, acc, 0, 0, 0);
    acc = __builtin_amdgcn_mfma_f32_16x16x32_bf16(Ah3, x5, acc, 0, 0, 0);
#pragma unroll
    for (int r = 0; r < 4; ++r) {
      float h = fmaxf(acc[r] + be[nt], 0.f);
      l0[r] = fmaf(h, w2v4[nt].x, l0[r]);
      l1[r] = fmaf(h, w2v4[nt].y, l1[r]);
    }
    bhp += 256; blp += 256;
    c0 = n0; c1 = n1; c2 = n2; c3 = n3; c4 = n4; c5 = n5;
  }
  // reduce over the 16 column-lanes (lane bits 0..3)
#pragma unroll
  for (int m = 1; m < 16; m <<= 1) {
#pragma unroll
    for (int r = 0; r < 4; ++r) {
      l0[r] += __shfl_xor(l0[r], m);
      l1[r] += __shfl_xor(l1[r], m);
    }
  }
  if ((lane & 15) == 0) {
    const float bb0 = b2[0], bb1 = b2[1];
    float rr[8];
#pragma unroll
    for (int r = 0; r < 4; ++r) {
      float a0 = l0[r] + bb0, a1 = l1[r] + bb1;
      float mx  = fmaxf(a0, a1);
      float e0  = __expf(a0 - mx), e1 = __expf(a1 - mx);
      float lse = mx + __logf(e0 + e1);
      rr[2 * r] = a0 - lse; rr[2 * r + 1] = a1 - lse;
    }
    const int base = blk * 16 + quad * 4;              // 4 consecutive samples
    float4* op = (float4*)(outf + base * 2);
    op[0] = make_float4(rr[0], rr[1], rr[2], rr[3]);
    op[1] = make_float4(rr[4], rr[5], rr[6], rr[7]);
  }
}

extern "C" void kernel_launch(void* const* d_in, const int* in_sizes, int n_in,
                              void* d_out, int out_size, void* d_ws, size_t ws_size,
                              hipStream_t stream)
{
  const float* scene = (const float*)d_in[0];
  const float* query = (const float*)d_in[1];
  // d_in[2..7] = phases/freqs: dead code w.r.t. the output, never read
  const float* sw = (const float*)d_in[8];
  const float* sb = (const float*)d_in[9];
  const float* qw = (const float*)d_in[10];
  const float* qb = (const float*)d_in[11];
  const float* w1 = (const float*)d_in[12];
  const float* b1 = (const float*)d_in[13];
  const float* w2 = (const float*)d_in[14];
  const float* b2 = (const float*)d_in[15];
  float* ws = (float*)d_ws;
  const int B = in_sizes[0] / 128;   // 65536

  hipLaunchKernelGGL(dtg_prep,  dim3(61), dim3(256), 0, stream, qw, qb, w1, b1, ws);
  hipLaunchKernelGGL(dtg_prep2, dim3(16), dim3(64),  0, stream, w1, ws);
  hipLaunchKernelGGL(dtg_main,  dim3(B / 16), dim3(64), 0, stream,
                     scene, query, sw, sb, w2, b2, ws, (float*)d_out);
}